// Round 10
// baseline (487.779 us; speedup 1.0000x reference)
//
#include <hip/hip_runtime.h>
#include <math.h>

#define BATCH 8
#define NCELLS 196
#define NCLS 20
#define HEADC 25

typedef __attribute__((ext_vector_type(8))) short short8;
typedef __attribute__((ext_vector_type(4))) float f32x4;
#define MFMA16(a,b,c) __builtin_amdgcn_mfma_f32_16x16x32_bf16(a,b,c,0,0,0)

#define GLOAD_LDS16(g, l) \
    __builtin_amdgcn_global_load_lds((const __attribute__((address_space(1))) void*)(g), \
                                     (__attribute__((address_space(3))) void*)(l), 16, 0, 0)

// ---- bf16 split helpers (RNE via bit ops; deterministic) ----
__device__ __forceinline__ unsigned short f2bf(float x) {
    union { float f; unsigned u; } a; a.f = x;
    unsigned r = a.u + 0x7FFFu + ((a.u >> 16) & 1u);
    return (unsigned short)(r >> 16);
}
__device__ __forceinline__ float bf2f(unsigned short h) {
    union { unsigned u; float f; } a; a.u = ((unsigned)h) << 16;
    return a.f;
}
__device__ __forceinline__ void split_bf(float x, unsigned short& h, unsigned short& l) {
    h = f2bf(x);
    l = f2bf(x - bf2f(h));
}

// ---- merged weight prep: all 4 conv weights in ONE launch ----
__device__ __forceinline__ void prep_one(const float* __restrict__ w, int CIN, int COUT,
                                         int idx, unsigned short* __restrict__ whi,
                                         unsigned short* __restrict__ wlo) {
    int G = COUT >> 4, CH = CIN >> 5;
    int j    = idx & 7;
    int lane = (idx >> 3) & 63;
    int fg   = idx >> 9;
    int g    = fg % G;
    int fc   = fg / G;
    int chunk = fc % CH;
    int plane = fc / CH;
    int co = g * 16 + (lane & 15);
    int ci = chunk * 32 + (lane >> 4) * 8 + j;
    int ky = plane / 3, kx = plane % 3;
    float v = w[((co * CIN + ci) * 3 + ky) * 3 + kx];
    unsigned short h, l; split_bf(v, h, l);
    whi[idx] = h; wlo[idx] = l;
}
__global__ void prep_all(const float* __restrict__ w2, const float* __restrict__ w3,
                         const float* __restrict__ w4, const float* __restrict__ w5,
                         unsigned short* __restrict__ w2h, unsigned short* __restrict__ w2l,
                         unsigned short* __restrict__ w3h, unsigned short* __restrict__ w3l,
                         unsigned short* __restrict__ w4h, unsigned short* __restrict__ w4l,
                         unsigned short* __restrict__ w5h, unsigned short* __restrict__ w5l) {
    int idx = blockIdx.x * 256 + threadIdx.x;
    const int n2 = 73728, n3 = 294912, n4 = 1179648, n5 = 2359296;
    if (idx < n2) { prep_one(w2, 64, 128, idx, w2h, w2l); return; }
    idx -= n2;
    if (idx < n3) { prep_one(w3, 128, 256, idx, w3h, w3l); return; }
    idx -= n3;
    if (idx < n4) { prep_one(w4, 256, 512, idx, w4h, w4l); return; }
    idx -= n4;
    if (idx < n5) { prep_one(w5, 512, 512, idx, w5h, w5l); }
}

// ---- conv1: 3->64, 448->224, fp32 compute, coalesced NHWC hi/lo stores ----
__global__ void conv1_kernel(const float* __restrict__ x, const float* __restrict__ w1,
                             unsigned short* __restrict__ ohi, unsigned short* __restrict__ olo) {
    __shared__ float sW[27][64];
    __shared__ float sX[3][3][66];
    int bid = blockIdx.x;
    int xseg = bid % 7;  bid /= 7;
    int oy   = bid % 224;
    int b    = bid / 224;
    int ox0  = xseg * 32;

    for (int e = threadIdx.x; e < 1728; e += 256) {
        int k = e >> 6, co = e & 63;
        sW[k][co] = w1[co * 27 + k];
    }
    for (int e = threadIdx.x; e < 594; e += 256) {
        int ci = e / 198;
        int r  = e - ci * 198;
        int ky = r / 66;
        int lx = r - ky * 66;
        int iy = 2 * oy + ky;
        int ix = 2 * ox0 + lx;
        float v = 0.f;
        if (lx < 65 && iy < 448 && ix < 448)
            v = x[(((size_t)b * 3 + ci) * 448 + iy) * 448 + ix];
        sX[ci][ky][lx] = v;
    }
    __syncthreads();

    int pxl = threadIdx.x >> 3;
    int cog = threadIdx.x & 7;
    float acc[8] = {0.f,0.f,0.f,0.f,0.f,0.f,0.f,0.f};
    #pragma unroll
    for (int ci = 0; ci < 3; ci++) {
        #pragma unroll
        for (int ky = 0; ky < 3; ky++) {
            const float* row = sX[ci][ky];
            #pragma unroll
            for (int kx = 0; kx < 3; kx++) {
                float iv = row[2 * pxl + kx];
                int k = (ci * 3 + ky) * 3 + kx;
                float4 wa = *(const float4*)&sW[k][cog * 8];
                float4 wb = *(const float4*)&sW[k][cog * 8 + 4];
                acc[0] += wa.x * iv; acc[1] += wa.y * iv; acc[2] += wa.z * iv; acc[3] += wa.w * iv;
                acc[4] += wb.x * iv; acc[5] += wb.y * iv; acc[6] += wb.z * iv; acc[7] += wb.w * iv;
            }
        }
    }
    union { unsigned short u[8]; uint4 v; } ph, pl;
    #pragma unroll
    for (int u = 0; u < 8; u++) {
        float v = fmaxf(acc[u], 0.f);
        split_bf(v, ph.u[u], pl.u[u]);
    }
    size_t base = ((size_t)(b * 224 + oy) * 224 + ox0 + pxl) * 64 + cog * 8;
    *(uint4*)&ohi[base] = ph.v;
    *(uint4*)&olo[base] = pl.v;
}

// ---- MFMA conv (R10): async global_load_lds staging + ping-pong LDS dbuf ----
// LDS dest is identity-contiguous (slot = element index e); the bank swizzle is
// applied on the SOURCE side: lane e fetches ci-group (e&3) ^ ((pxi>>1)&3), so
// reads keep R9's conflict-free pattern. One __syncthreads per chunk; chunk k+1
// loads drain during chunk k's 216-MFMA run. OOB halo lanes ds_write zeros.
template<int CIN, int COUT, int HIN, int WIN, int KSPLIT, bool PARTIAL>
__launch_bounds__(256, 2)
__global__ void conv_mfma(const unsigned short* __restrict__ ahi, const unsigned short* __restrict__ alo,
                          const unsigned short* __restrict__ whi, const unsigned short* __restrict__ wlo,
                          unsigned short* __restrict__ ohi, unsigned short* __restrict__ olo,
                          float* __restrict__ part) {
    constexpr int HOUT = HIN / 2, WOUT = WIN / 2;
    constexpr int TX = (WOUT + 7) / 8, TY = (HOUT + 7) / 8;
    constexpr int COG = COUT / 128;
    constexpr int CH_TOT = CIN / 32;
    constexpr int CH = CH_TOT / KSPLIT;
    constexpr int G = COUT / 16;
    constexpr int UNITS = 17 * 17 * 4;            // 1156 16B-units per hi/lo plane
    constexpr size_t PSZ = (size_t)BATCH * HOUT * WOUT * COUT;

    __shared__ __align__(16) unsigned short sA[2][2][UNITS * 8];   // [buf][hi/lo] = 73,984 B

    int bid = blockIdx.x;
    int ks  = bid % KSPLIT; bid /= KSPLIT;
    int txi = bid % TX;     bid /= TX;
    int tyi = bid % TY;     bid /= TY;
    int cg  = bid % COG;
    int b   = bid / COG;
    int oy0 = tyi * 8, ox0 = txi * 8;
    int iy0 = oy0 * 2, ix0 = ox0 * 2;

    int tid = threadIdx.x;
    int w   = tid >> 6;
    int lane = tid & 63;
    int n = lane & 15, quad = lane >> 4;
    int cohalf = w & 1;
    int pxhalf = w >> 1;

    int oyl[2], oxl[2], pbase[2];
    #pragma unroll
    for (int t = 0; t < 2; t++) {
        int nt = pxhalf * 2 + t;
        int oy_off = (nt >> 1) * 4 + (n >> 2);
        int ox_off = (nt & 1) * 4 + (n & 3);
        oyl[t] = oy0 + oy_off;
        oxl[t] = ox0 + ox_off;
        pbase[t] = 2 * oy_off * 17 + 2 * ox_off;
    }

    f32x4 zero = {0.f, 0.f, 0.f, 0.f};
    f32x4 acc[4][2];
    #pragma unroll
    for (int g = 0; g < 4; g++)
        #pragma unroll
        for (int t = 0; t < 2; t++) acc[g][t] = zero;

    int g0 = cg * 8 + cohalf * 4;

    auto stage = [&](int ch, int buf) {
        int ci0 = (ks * CH + ch) * 32;
        #pragma unroll
        for (int m = 0; m < (UNITS + 255) / 256; m++) {
            int e = m * 256 + tid;
            if (e < UNITS) {
                int pxi = e >> 2, gsl = e & 3;
                int grp = gsl ^ ((pxi >> 1) & 3);
                int liy = pxi / 17, lix = pxi - liy * 17;
                int iy = iy0 + liy, ix = ix0 + lix;
                if (iy < HIN && ix < WIN) {
                    size_t off = ((size_t)(b * HIN + iy) * WIN + ix) * CIN + ci0 + grp * 8;
                    int ebase = m * 256 + (tid & 192);   // wave-uniform dest base
                    GLOAD_LDS16(ahi + off, &sA[buf][0][ebase * 8]);
                    GLOAD_LDS16(alo + off, &sA[buf][1][ebase * 8]);
                } else {
                    uint4 z = make_uint4(0u, 0u, 0u, 0u);
                    *(uint4*)&sA[buf][0][e * 8] = z;
                    *(uint4*)&sA[buf][1][e * 8] = z;
                }
            }
        }
    };

    stage(0, 0);
    int pb = 0;
    for (int ch = 0; ch < CH; ch++) {
        __syncthreads();                       // drains vmcnt (staging) + lgkm
        if (ch + 1 < CH) stage(ch + 1, pb ^ 1);
        int chunk = ks * CH + ch;
        #pragma unroll
        for (int pl = 0; pl < 9; pl++) {
            size_t fbase = ((size_t)(pl * CH_TOT + chunk) * G + g0) * 512 + lane * 8;
            short8 Ah[4], Al[4];
            #pragma unroll
            for (int g = 0; g < 4; g++) {
                Ah[g] = *(const short8*)(whi + fbase + (size_t)g * 512);
                Al[g] = *(const short8*)(wlo + fbase + (size_t)g * 512);
            }
            int dp = (pl / 3) * 17 + (pl % 3);
            short8 Bh[2], Bl[2];
            #pragma unroll
            for (int t = 0; t < 2; t++) {
                int p = pbase[t] + dp;
                int u = p * 4 + (quad ^ ((p >> 1) & 3));
                Bh[t] = *(const short8*)&sA[pb][0][u * 8];
                Bl[t] = *(const short8*)&sA[pb][1][u * 8];
            }
            #pragma unroll
            for (int g = 0; g < 4; g++) {
                #pragma unroll
                for (int t = 0; t < 2; t++) {
                    acc[g][t] = MFMA16(Ah[g], Bh[t], acc[g][t]);
                    acc[g][t] = MFMA16(Ah[g], Bl[t], acc[g][t]);
                    acc[g][t] = MFMA16(Al[g], Bh[t], acc[g][t]);
                }
            }
        }
        pb ^= 1;
    }

    int cob = cg * 128 + cohalf * 64;
    #pragma unroll
    for (int g = 0; g < 4; g++) {
        #pragma unroll
        for (int t = 0; t < 2; t++) {
            if (oyl[t] >= HOUT || oxl[t] >= WOUT) continue;
            size_t base = ((size_t)(b * HOUT + oyl[t]) * WOUT + oxl[t]) * COUT
                          + cob + g * 16 + quad * 4;
            if (PARTIAL) {
                *(f32x4*)&part[(size_t)ks * PSZ + base] = acc[g][t];
            } else {
                unsigned long long h64 = 0ull, l64 = 0ull;
                #pragma unroll
                for (int r = 0; r < 4; r++) {
                    float v = fmaxf(acc[g][t][r], 0.f);
                    unsigned short hh, ll; split_bf(v, hh, ll);
                    h64 |= ((unsigned long long)hh) << (16 * r);
                    l64 |= ((unsigned long long)ll) << (16 * r);
                }
                *(unsigned long long*)&ohi[base] = h64;
                *(unsigned long long*)&olo[base] = l64;
            }
        }
    }
}

// ---- reduce KS K-split fp32 partials -> ReLU -> hi/lo bf16 ----
template<int KS>
__global__ void reduceN_split(const float* __restrict__ p, unsigned short* __restrict__ oh,
                              unsigned short* __restrict__ ol, int n) {
    int n4 = n >> 2;
    int i = blockIdx.x * 256 + threadIdx.x;
    if (i >= n4) return;
    const float4* p4 = (const float4*)p;
    float4 s = p4[i];
    #pragma unroll
    for (int k = 1; k < KS; k++) {
        float4 t = p4[i + (size_t)k * n4];
        s.x += t.x; s.y += t.y; s.z += t.z; s.w += t.w;
    }
    float v[4] = { fmaxf(s.x,0.f), fmaxf(s.y,0.f), fmaxf(s.z,0.f), fmaxf(s.w,0.f) };
    unsigned long long h64 = 0ull, l64 = 0ull;
    #pragma unroll
    for (int r = 0; r < 4; r++) {
        unsigned short hh, ll; split_bf(v[r], hh, ll);
        h64 |= ((unsigned long long)hh) << (16 * r);
        l64 |= ((unsigned long long)ll) << (16 * r);
    }
    *(unsigned long long*)&oh[i * 4] = h64;
    *(unsigned long long*)&ol[i * 4] = l64;
}

// ---- fused 1x1 head + decode ----
__global__ void head_decode_kernel(const unsigned short* __restrict__ ah,
                                   const unsigned short* __restrict__ al,
                                   const float* __restrict__ wh,
                                   float* __restrict__ out, float* __restrict__ cls) {
    int wave = threadIdx.x >> 6;
    int lane = threadIdx.x & 63;
    int cellid = blockIdx.x * 4 + wave;
    float acc[HEADC];
    #pragma unroll
    for (int c = 0; c < HEADC; c++) acc[c] = 0.f;
    for (int it = 0; it < 8; it++) {
        int ci = it * 64 + lane;
        size_t idx = (size_t)cellid * 512 + ci;
        float a = bf2f(ah[idx]) + bf2f(al[idx]);
        #pragma unroll
        for (int c = 0; c < HEADC; c++) acc[c] += a * wh[c * 512 + ci];
    }
    #pragma unroll
    for (int c = 0; c < HEADC; c++) {
        float v = acc[c];
        v += __shfl_down(v, 32); v += __shfl_down(v, 16); v += __shfl_down(v, 8);
        v += __shfl_down(v, 4);  v += __shfl_down(v, 2);  v += __shfl_down(v, 1);
        acc[c] = v;
    }
    if (lane == 0) {
        int cell = cellid % NCELLS;
        int gx = cell % 14, gy = cell / 14;
        float conf = 1.f / (1.f + expf(-acc[0]));
        float m = acc[1];
        #pragma unroll
        for (int c = 1; c < NCLS; c++) m = fmaxf(m, acc[1 + c]);
        float e[NCLS], s = 0.f;
        #pragma unroll
        for (int c = 0; c < NCLS; c++) { e[c] = expf(acc[1 + c] - m); s += e[c]; }
        float inv = conf / s;
        #pragma unroll
        for (int c = 0; c < NCLS; c++) cls[(size_t)cellid * NCLS + c] = e[c] * inv;
        float cx = (1.f / (1.f + expf(-acc[21])) + gx) * 32.f;
        float cy = (1.f / (1.f + expf(-acc[22])) + gy) * 32.f;
        float bw = expf(acc[23]) * 32.f;
        float bh = expf(acc[24]) * 32.f;
        float x1 = (cx - 0.5f * bw) / 448.f, y1 = (cy - 0.5f * bh) / 448.f;
        float x2 = (cx + 0.5f * bw) / 448.f, y2 = (cy + 0.5f * bh) / 448.f;
        x1 = fminf(fmaxf(x1, 0.f), 1.f); y1 = fminf(fmaxf(y1, 0.f), 1.f);
        x2 = fminf(fmaxf(x2, 0.f), 1.f); y2 = fminf(fmaxf(y2, 0.f), 1.f);
        float* o = out + (size_t)cellid * 24;
        o[0] = x1; o[1] = y1; o[2] = x2; o[3] = y2;
    }
}

// ---- IoU ----
__global__ void iou_kernel(const float* __restrict__ out, float* __restrict__ iou) {
    int idx = blockIdx.x * 256 + threadIdx.x;
    if (idx >= BATCH * NCELLS * NCELLS) return;
    int j = idx % NCELLS;
    int i = (idx / NCELLS) % NCELLS;
    int b = idx / (NCELLS * NCELLS);
    const float* bi = out + (((size_t)b * NCELLS) + i) * 24;
    const float* bj = out + (((size_t)b * NCELLS) + j) * 24;
    float ai = fmaxf(bi[2] - bi[0], 0.f) * fmaxf(bi[3] - bi[1], 0.f);
    float aj = fmaxf(bj[2] - bj[0], 0.f) * fmaxf(bj[3] - bj[1], 0.f);
    float ix1 = fmaxf(bi[0], bj[0]), iy1 = fmaxf(bi[1], bj[1]);
    float ix2 = fminf(bi[2], bj[2]), iy2 = fminf(bi[3], bj[3]);
    float inter = fmaxf(ix2 - ix1, 0.f) * fmaxf(iy2 - iy1, 0.f);
    iou[idx] = inter / (ai + aj - inter + 1e-14f);
}

// ---- NMS: bitmask formulation ----
__global__ void nms_kernel(const float* __restrict__ cls, const float* __restrict__ iou,
                           float* __restrict__ out) {
    int b = blockIdx.x / NCLS;
    int c = blockIdx.x % NCLS;
    __shared__ float sc[NCELLS];
    __shared__ float ssort[NCELLS];
    __shared__ int   ord[NCELLS];
    __shared__ __align__(16) unsigned long long smask[NCELLS][4];
    int j = threadIdx.x;
    int lane = j & 63;
    int w = j >> 6;
    float sj = 0.f;
    if (j < NCELLS) {
        sj = cls[(((size_t)b * NCELLS) + j) * NCLS + c];
        sc[j] = sj;
    }
    __syncthreads();
    if (j < NCELLS) {
        int r = 0;
        for (int k = 0; k < NCELLS; k++) {
            float sk = sc[k];
            r += (sk > sj) || (sk == sj && k < j);
        }
        ord[r] = j; ssort[r] = sj;
    }
    __syncthreads();
    const float* iob = iou + (size_t)b * NCELLS * NCELLS;
    int oc[4];
    #pragma unroll
    for (int k = 0; k < 4; k++) {
        int cidx = k * 64 + lane;
        oc[k] = (cidx < NCELLS) ? ord[cidx] : 0;
    }
    for (int i = w; i < NCELLS; i += 4) {
        const float* rowp = iob + ord[i] * NCELLS;
        #pragma unroll
        for (int k = 0; k < 4; k++) {
            int cidx = k * 64 + lane;
            bool sup = false;
            if (cidx < NCELLS && cidx > i)
                sup = rowp[oc[k]] > 0.5f;
            unsigned long long m = __ballot(sup);
            if (lane == 0) smask[i][k] = m;
        }
    }
    __syncthreads();
    unsigned long long keep[4];
    #pragma unroll
    for (int k = 0; k < 4; k++) {
        int cidx = k * 64 + lane;
        bool valid = (cidx < NCELLS) && (ssort[cidx] > 0.01f);
        keep[k] = __ballot(valid);
    }
    #pragma unroll
    for (int wi = 0; wi < 4; wi++) {
        int base = wi * 64;
        int lim = (NCELLS - base < 64) ? (NCELLS - base) : 64;
        for (int t = 0; t < lim; t++) {
            if ((keep[wi] >> t) & 1ull) {
                int i = base + t;
                keep[0] &= ~smask[i][0];
                keep[1] &= ~smask[i][1];
                keep[2] &= ~smask[i][2];
                keep[3] &= ~smask[i][3];
            }
        }
    }
    if (j < NCELLS) {
        bool kept = (keep[w] >> lane) & 1ull;
        out[(((size_t)b * NCELLS) + ord[j]) * 24 + 4 + c] = kept ? ssort[j] : 0.f;
    }
}

// ---- launch ----
extern "C" void kernel_launch(void* const* d_in, const int* in_sizes, int n_in,
                              void* d_out, int out_size, void* d_ws, size_t ws_size,
                              hipStream_t stream) {
    const float* x  = (const float*)d_in[0];
    const float* w1 = (const float*)d_in[1];
    const float* w2 = (const float*)d_in[2];
    const float* w3 = (const float*)d_in[3];
    const float* w4 = (const float*)d_in[4];
    const float* w5 = (const float*)d_in[5];
    const float* wh = (const float*)d_in[6];
    float* out = (float*)d_out;
    char* base = (char*)d_ws;

    // region A (0 .. 102,760,448)
    unsigned short* a1h = (unsigned short*)(base);
    unsigned short* a1l = a1h + 25690112;
    unsigned short* a3h = (unsigned short*)(base);          // overlays a1 (dead after conv2)
    unsigned short* a3l = a3h + 6422528;
    float* part4 = (float*)(base + 25690112);               // 2 x 3,211,264 fp32
    float* part5 = (float*)(base);                          // 8 x 802,816 fp32 (a3 dead)
    unsigned short* a5h = (unsigned short*)(base + 51380224);
    unsigned short* a5l = a5h + 802816;
    float* clsb = (float*)(base + 54746240);
    float* ioub = (float*)(base + 54871680);
    // region B (102,760,448 .. 154,140,672)
    unsigned short* a2h = (unsigned short*)(base + 102760448);
    unsigned short* a2l = a2h + 12845056;
    unsigned short* a4h = (unsigned short*)(base + 102760448);  // overlays a2 (dead after conv3)
    unsigned short* a4l = a4h + 3211264;
    // weights
    unsigned short* w2h = (unsigned short*)(base + 154140672);
    unsigned short* w3h = w2h + 73728;
    unsigned short* w4h = w3h + 294912;
    unsigned short* w5h = w4h + 1179648;
    unsigned short* w2l = (unsigned short*)(base + 161955840);
    unsigned short* w3l = w2l + 73728;
    unsigned short* w4l = w3l + 294912;
    unsigned short* w5l = w4l + 1179648;

    prep_all<<<15264, 256, 0, stream>>>(w2, w3, w4, w5,
                                        w2h, w2l, w3h, w3l, w4h, w4l, w5h, w5l);

    conv1_kernel<<<12544, 256, 0, stream>>>(x, w1, a1h, a1l);

    conv_mfma<64, 128, 224, 224, 1, false><<<1568, 256, 0, stream>>>(
        a1h, a1l, w2h, w2l, a2h, a2l, nullptr);
    conv_mfma<128, 256, 112, 112, 1, false><<<784, 256, 0, stream>>>(
        a2h, a2l, w3h, w3l, a3h, a3l, nullptr);
    conv_mfma<256, 512, 56, 56, 2, true><<<1024, 256, 0, stream>>>(
        a3h, a3l, w4h, w4l, nullptr, nullptr, part4);
    reduceN_split<2><<<3136, 256, 0, stream>>>(part4, a4h, a4l, 3211264);
    conv_mfma<512, 512, 28, 28, 8, true><<<1024, 256, 0, stream>>>(
        a4h, a4l, w5h, w5l, nullptr, nullptr, part5);
    reduceN_split<8><<<784, 256, 0, stream>>>(part5, a5h, a5l, 802816);

    head_decode_kernel<<<392, 256, 0, stream>>>(a5h, a5l, wh, out, clsb);
    iou_kernel<<<1201, 256, 0, stream>>>(out, ioub);
    nms_kernel<<<160, 256, 0, stream>>>(clsb, ioub, out);
}

// Round 11
// 445.895 us; speedup vs baseline: 1.0939x; 1.0939x over previous
//
#include <hip/hip_runtime.h>
#include <math.h>

#define BATCH 8
#define NCELLS 196
#define NCLS 20
#define HEADC 25

typedef __attribute__((ext_vector_type(8))) short short8;
typedef __attribute__((ext_vector_type(4))) float f32x4;
#define MFMA16(a,b,c) __builtin_amdgcn_mfma_f32_16x16x32_bf16(a,b,c,0,0,0)

// ---- bf16 split helpers (RNE via bit ops; deterministic) ----
__device__ __forceinline__ unsigned short f2bf(float x) {
    union { float f; unsigned u; } a; a.f = x;
    unsigned r = a.u + 0x7FFFu + ((a.u >> 16) & 1u);
    return (unsigned short)(r >> 16);
}
__device__ __forceinline__ float bf2f(unsigned short h) {
    union { unsigned u; float f; } a; a.u = ((unsigned)h) << 16;
    return a.f;
}
__device__ __forceinline__ void split_bf(float x, unsigned short& h, unsigned short& l) {
    h = f2bf(x);
    l = f2bf(x - bf2f(h));
}

// ---- merged weight prep: all 4 conv weights in ONE launch ----
__device__ __forceinline__ void prep_one(const float* __restrict__ w, int CIN, int COUT,
                                         int idx, unsigned short* __restrict__ whi,
                                         unsigned short* __restrict__ wlo) {
    int G = COUT >> 4, CH = CIN >> 5;
    int j    = idx & 7;
    int lane = (idx >> 3) & 63;
    int fg   = idx >> 9;
    int g    = fg % G;
    int fc   = fg / G;
    int chunk = fc % CH;
    int plane = fc / CH;
    int co = g * 16 + (lane & 15);
    int ci = chunk * 32 + (lane >> 4) * 8 + j;
    int ky = plane / 3, kx = plane % 3;
    float v = w[((co * CIN + ci) * 3 + ky) * 3 + kx];
    unsigned short h, l; split_bf(v, h, l);
    whi[idx] = h; wlo[idx] = l;
}
__global__ void prep_all(const float* __restrict__ w2, const float* __restrict__ w3,
                         const float* __restrict__ w4, const float* __restrict__ w5,
                         unsigned short* __restrict__ w2h, unsigned short* __restrict__ w2l,
                         unsigned short* __restrict__ w3h, unsigned short* __restrict__ w3l,
                         unsigned short* __restrict__ w4h, unsigned short* __restrict__ w4l,
                         unsigned short* __restrict__ w5h, unsigned short* __restrict__ w5l) {
    int idx = blockIdx.x * 256 + threadIdx.x;
    const int n2 = 73728, n3 = 294912, n4 = 1179648, n5 = 2359296;
    if (idx < n2) { prep_one(w2, 64, 128, idx, w2h, w2l); return; }
    idx -= n2;
    if (idx < n3) { prep_one(w3, 128, 256, idx, w3h, w3l); return; }
    idx -= n3;
    if (idx < n4) { prep_one(w4, 256, 512, idx, w4h, w4l); return; }
    idx -= n4;
    if (idx < n5) { prep_one(w5, 512, 512, idx, w5h, w5l); }
}

// ---- conv1: 3->64, 448->224, fp32 compute, coalesced NHWC hi/lo stores ----
__global__ void conv1_kernel(const float* __restrict__ x, const float* __restrict__ w1,
                             unsigned short* __restrict__ ohi, unsigned short* __restrict__ olo) {
    __shared__ float sW[27][64];
    __shared__ float sX[3][3][66];
    int bid = blockIdx.x;
    int xseg = bid % 7;  bid /= 7;
    int oy   = bid % 224;
    int b    = bid / 224;
    int ox0  = xseg * 32;

    for (int e = threadIdx.x; e < 1728; e += 256) {
        int k = e >> 6, co = e & 63;
        sW[k][co] = w1[co * 27 + k];
    }
    for (int e = threadIdx.x; e < 594; e += 256) {
        int ci = e / 198;
        int r  = e - ci * 198;
        int ky = r / 66;
        int lx = r - ky * 66;
        int iy = 2 * oy + ky;
        int ix = 2 * ox0 + lx;
        float v = 0.f;
        if (lx < 65 && iy < 448 && ix < 448)
            v = x[(((size_t)b * 3 + ci) * 448 + iy) * 448 + ix];
        sX[ci][ky][lx] = v;
    }
    __syncthreads();

    int pxl = threadIdx.x >> 3;
    int cog = threadIdx.x & 7;
    float acc[8] = {0.f,0.f,0.f,0.f,0.f,0.f,0.f,0.f};
    #pragma unroll
    for (int ci = 0; ci < 3; ci++) {
        #pragma unroll
        for (int ky = 0; ky < 3; ky++) {
            const float* row = sX[ci][ky];
            #pragma unroll
            for (int kx = 0; kx < 3; kx++) {
                float iv = row[2 * pxl + kx];
                int k = (ci * 3 + ky) * 3 + kx;
                float4 wa = *(const float4*)&sW[k][cog * 8];
                float4 wb = *(const float4*)&sW[k][cog * 8 + 4];
                acc[0] += wa.x * iv; acc[1] += wa.y * iv; acc[2] += wa.z * iv; acc[3] += wa.w * iv;
                acc[4] += wb.x * iv; acc[5] += wb.y * iv; acc[6] += wb.z * iv; acc[7] += wb.w * iv;
            }
        }
    }
    union { unsigned short u[8]; uint4 v; } ph, pl;
    #pragma unroll
    for (int u = 0; u < 8; u++) {
        float v = fmaxf(acc[u], 0.f);
        split_bf(v, ph.u[u], pl.u[u]);
    }
    size_t base = ((size_t)(b * 224 + oy) * 224 + ox0 + pxl) * 64 + cog * 8;
    *(uint4*)&ohi[base] = ph.v;
    *(uint4*)&olo[base] = pl.v;
}

// ---- MFMA conv (R11): R8-exact structure + ring-3 A-fragment plane prefetch ----
// R8 proved best (4 blocks/CU, 37KB LDS, co-sliced waves). R9 (repartition) and
// R10 (async dbuf) both regressed — reverted. New: A-frag loads for plane p+3
// issue while plane p's MFMAs run, pulling ~200cyc L2 latency off the critical
// path (compiler alone kept only ~1 plane in flight: VGPR_Count was 52-56).
template<int CIN, int COUT, int HIN, int WIN, int KSPLIT, bool PARTIAL>
__launch_bounds__(256, 4)
__global__ void conv_mfma(const unsigned short* __restrict__ ahi, const unsigned short* __restrict__ alo,
                          const unsigned short* __restrict__ whi, const unsigned short* __restrict__ wlo,
                          unsigned short* __restrict__ ohi, unsigned short* __restrict__ olo,
                          float* __restrict__ part) {
    constexpr int HOUT = HIN / 2, WOUT = WIN / 2;
    constexpr int TX = (WOUT + 7) / 8, TY = (HOUT + 7) / 8;
    constexpr int COG = COUT / 128;
    constexpr int CH_TOT = CIN / 32;
    constexpr int CH = CH_TOT / KSPLIT;
    constexpr int G = COUT / 16;
    constexpr int PLANE_E = 17 * 17 * 32;
    constexpr size_t PSZ = (size_t)BATCH * HOUT * WOUT * COUT;

    __shared__ __align__(16) unsigned short sA[2 * PLANE_E];

    int bid = blockIdx.x;
    int ks  = bid % KSPLIT; bid /= KSPLIT;
    int txi = bid % TX;     bid /= TX;
    int tyi = bid % TY;     bid /= TY;
    int cg  = bid % COG;
    int b   = bid / COG;
    int oy0 = tyi * 8, ox0 = txi * 8;
    int iy0 = oy0 * 2, ix0 = ox0 * 2;

    int tid = threadIdx.x;
    int w   = tid >> 6;
    int lane = tid & 63;
    int n = lane & 15, quad = lane >> 4;

    int oyl[4], oxl[4], pbase[4];
    #pragma unroll
    for (int nt = 0; nt < 4; nt++) {
        int oyq = nt >> 1, oxq = nt & 1;
        int oy_off = oyq * 4 + (n >> 2);
        int ox_off = oxq * 4 + (n & 3);
        oyl[nt] = oy0 + oy_off;
        oxl[nt] = ox0 + ox_off;
        pbase[nt] = 2 * oy_off * 17 + 2 * ox_off;
    }

    f32x4 zero = {0.f, 0.f, 0.f, 0.f};
    f32x4 acc[2][4];
    #pragma unroll
    for (int ct = 0; ct < 2; ct++)
        #pragma unroll
        for (int nt = 0; nt < 4; nt++) acc[ct][nt] = zero;

    int g0 = cg * 8 + w * 2;

    for (int ch = 0; ch < CH; ch++) {
        int chunk = ks * CH + ch;
        int ci0 = chunk * 32;
        __syncthreads();
        // ---- stage act tile: 17x17 px x 32 ci, hi+lo, swizzled 16B units ----
        for (int e = tid; e < 17 * 17 * 8; e += 256) {
            int pxi = e >> 3, grp = e & 7;
            int liy = pxi / 17, lix = pxi - liy * 17;
            int iy = iy0 + liy, ix = ix0 + lix;
            uint4 v = make_uint4(0u, 0u, 0u, 0u);
            if (iy < HIN && ix < WIN) {
                const unsigned short* src = ((grp & 4) ? alo : ahi)
                    + ((size_t)(b * HIN + iy) * WIN + ix) * CIN + ci0 + (grp & 3) * 8;
                v = *(const uint4*)src;
            }
            int u = pxi * 4 + ((grp & 3) ^ ((pxi >> 1) & 3));
            *(uint4*)&sA[((grp >> 2) ? PLANE_E : 0) + u * 8] = v;
        }
        __syncthreads();
        // ---- ring-3 A prefetch + 9 kernel planes ----
        short8 Ah[3][2], Al[3][2];
        auto loadA = [&](int pl, int slot) {
            size_t fbase = ((size_t)(pl * CH_TOT + chunk) * G + g0) * 512 + lane * 8;
            Ah[slot][0] = *(const short8*)(whi + fbase);
            Ah[slot][1] = *(const short8*)(whi + fbase + 512);
            Al[slot][0] = *(const short8*)(wlo + fbase);
            Al[slot][1] = *(const short8*)(wlo + fbase + 512);
        };
        loadA(0, 0); loadA(1, 1); loadA(2, 2);
        #pragma unroll
        for (int pl = 0; pl < 9; pl++) {
            const int slot = pl % 3;
            int dp = (pl / 3) * 17 + (pl % 3);
            #pragma unroll
            for (int nt = 0; nt < 4; nt++) {
                int p = pbase[nt] + dp;
                int u = p * 4 + (quad ^ ((p >> 1) & 3));
                short8 Bh = *(const short8*)&sA[u * 8];
                short8 Bl = *(const short8*)&sA[PLANE_E + u * 8];
                acc[0][nt] = MFMA16(Ah[slot][0], Bh, acc[0][nt]);
                acc[0][nt] = MFMA16(Ah[slot][0], Bl, acc[0][nt]);
                acc[0][nt] = MFMA16(Al[slot][0], Bh, acc[0][nt]);
                acc[1][nt] = MFMA16(Ah[slot][1], Bh, acc[1][nt]);
                acc[1][nt] = MFMA16(Ah[slot][1], Bl, acc[1][nt]);
                acc[1][nt] = MFMA16(Al[slot][1], Bh, acc[1][nt]);
            }
            if (pl + 3 < 9) loadA(pl + 3, slot);
        }
    }
    int cob = cg * 128 + w * 32;
    #pragma unroll
    for (int ct = 0; ct < 2; ct++) {
        #pragma unroll
        for (int nt = 0; nt < 4; nt++) {
            if (oyl[nt] >= HOUT || oxl[nt] >= WOUT) continue;
            size_t base = ((size_t)(b * HOUT + oyl[nt]) * WOUT + oxl[nt]) * COUT
                          + cob + ct * 16 + quad * 4;
            if (PARTIAL) {
                *(f32x4*)&part[(size_t)ks * PSZ + base] = acc[ct][nt];
            } else {
                unsigned long long h64 = 0ull, l64 = 0ull;
                #pragma unroll
                for (int r = 0; r < 4; r++) {
                    float v = fmaxf(acc[ct][nt][r], 0.f);
                    unsigned short hh, ll; split_bf(v, hh, ll);
                    h64 |= ((unsigned long long)hh) << (16 * r);
                    l64 |= ((unsigned long long)ll) << (16 * r);
                }
                *(unsigned long long*)&ohi[base] = h64;
                *(unsigned long long*)&olo[base] = l64;
            }
        }
    }
}

// ---- reduce KS K-split fp32 partials -> ReLU -> hi/lo bf16 ----
template<int KS>
__global__ void reduceN_split(const float* __restrict__ p, unsigned short* __restrict__ oh,
                              unsigned short* __restrict__ ol, int n) {
    int n4 = n >> 2;
    int i = blockIdx.x * 256 + threadIdx.x;
    if (i >= n4) return;
    const float4* p4 = (const float4*)p;
    float4 s = p4[i];
    #pragma unroll
    for (int k = 1; k < KS; k++) {
        float4 t = p4[i + (size_t)k * n4];
        s.x += t.x; s.y += t.y; s.z += t.z; s.w += t.w;
    }
    float v[4] = { fmaxf(s.x,0.f), fmaxf(s.y,0.f), fmaxf(s.z,0.f), fmaxf(s.w,0.f) };
    unsigned long long h64 = 0ull, l64 = 0ull;
    #pragma unroll
    for (int r = 0; r < 4; r++) {
        unsigned short hh, ll; split_bf(v[r], hh, ll);
        h64 |= ((unsigned long long)hh) << (16 * r);
        l64 |= ((unsigned long long)ll) << (16 * r);
    }
    *(unsigned long long*)&oh[i * 4] = h64;
    *(unsigned long long*)&ol[i * 4] = l64;
}

// ---- fused 1x1 head + decode ----
__global__ void head_decode_kernel(const unsigned short* __restrict__ ah,
                                   const unsigned short* __restrict__ al,
                                   const float* __restrict__ wh,
                                   float* __restrict__ out, float* __restrict__ cls) {
    int wave = threadIdx.x >> 6;
    int lane = threadIdx.x & 63;
    int cellid = blockIdx.x * 4 + wave;
    float acc[HEADC];
    #pragma unroll
    for (int c = 0; c < HEADC; c++) acc[c] = 0.f;
    for (int it = 0; it < 8; it++) {
        int ci = it * 64 + lane;
        size_t idx = (size_t)cellid * 512 + ci;
        float a = bf2f(ah[idx]) + bf2f(al[idx]);
        #pragma unroll
        for (int c = 0; c < HEADC; c++) acc[c] += a * wh[c * 512 + ci];
    }
    #pragma unroll
    for (int c = 0; c < HEADC; c++) {
        float v = acc[c];
        v += __shfl_down(v, 32); v += __shfl_down(v, 16); v += __shfl_down(v, 8);
        v += __shfl_down(v, 4);  v += __shfl_down(v, 2);  v += __shfl_down(v, 1);
        acc[c] = v;
    }
    if (lane == 0) {
        int cell = cellid % NCELLS;
        int gx = cell % 14, gy = cell / 14;
        float conf = 1.f / (1.f + expf(-acc[0]));
        float m = acc[1];
        #pragma unroll
        for (int c = 1; c < NCLS; c++) m = fmaxf(m, acc[1 + c]);
        float e[NCLS], s = 0.f;
        #pragma unroll
        for (int c = 0; c < NCLS; c++) { e[c] = expf(acc[1 + c] - m); s += e[c]; }
        float inv = conf / s;
        #pragma unroll
        for (int c = 0; c < NCLS; c++) cls[(size_t)cellid * NCLS + c] = e[c] * inv;
        float cx = (1.f / (1.f + expf(-acc[21])) + gx) * 32.f;
        float cy = (1.f / (1.f + expf(-acc[22])) + gy) * 32.f;
        float bw = expf(acc[23]) * 32.f;
        float bh = expf(acc[24]) * 32.f;
        float x1 = (cx - 0.5f * bw) / 448.f, y1 = (cy - 0.5f * bh) / 448.f;
        float x2 = (cx + 0.5f * bw) / 448.f, y2 = (cy + 0.5f * bh) / 448.f;
        x1 = fminf(fmaxf(x1, 0.f), 1.f); y1 = fminf(fmaxf(y1, 0.f), 1.f);
        x2 = fminf(fmaxf(x2, 0.f), 1.f); y2 = fminf(fmaxf(y2, 0.f), 1.f);
        float* o = out + (size_t)cellid * 24;
        o[0] = x1; o[1] = y1; o[2] = x2; o[3] = y2;
    }
}

// ---- NMS with inline IoU (R11): iou_kernel fused away; boxes staged in LDS ----
__global__ void nms_kernel(const float* __restrict__ cls, const float* __restrict__ boxes,
                           float* __restrict__ out) {
    int b = blockIdx.x / NCLS;
    int c = blockIdx.x % NCLS;
    __shared__ float sc[NCELLS];
    __shared__ float ssort[NCELLS];
    __shared__ int   ord[NCELLS];
    __shared__ __align__(16) float sbox[NCELLS][4];
    __shared__ float sarea[NCELLS];
    __shared__ __align__(16) unsigned long long smask[NCELLS][4];
    int j = threadIdx.x;
    int lane = j & 63;
    int w = j >> 6;
    float sj = 0.f;
    if (j < NCELLS) {
        sj = cls[(((size_t)b * NCELLS) + j) * NCLS + c];
        sc[j] = sj;
        float4 bx = *(const float4*)&boxes[(((size_t)b * NCELLS) + j) * 24];
        *(float4*)sbox[j] = bx;
        sarea[j] = fmaxf(bx.z - bx.x, 0.f) * fmaxf(bx.w - bx.y, 0.f);
    }
    __syncthreads();
    if (j < NCELLS) {
        int r = 0;
        for (int k = 0; k < NCELLS; k++) {
            float sk = sc[k];
            r += (sk > sj) || (sk == sj && k < j);
        }
        ord[r] = j; ssort[r] = sj;
    }
    __syncthreads();
    int oc[4]; float bx1[4], by1[4], bx2[4], by2[4], bar[4];
    #pragma unroll
    for (int k = 0; k < 4; k++) {
        int cidx = k * 64 + lane;
        oc[k] = (cidx < NCELLS) ? ord[cidx] : 0;
        bx1[k] = sbox[oc[k]][0]; by1[k] = sbox[oc[k]][1];
        bx2[k] = sbox[oc[k]][2]; by2[k] = sbox[oc[k]][3];
        bar[k] = sarea[oc[k]];
    }
    for (int i = w; i < NCELLS; i += 4) {
        int oi = ord[i];
        float ix1 = sbox[oi][0], iy1 = sbox[oi][1];
        float ix2 = sbox[oi][2], iy2 = sbox[oi][3];
        float ia  = sarea[oi];
        #pragma unroll
        for (int k = 0; k < 4; k++) {
            int cidx = k * 64 + lane;
            bool sup = false;
            if (cidx < NCELLS && cidx > i) {
                float xx1 = fmaxf(ix1, bx1[k]), yy1 = fmaxf(iy1, by1[k]);
                float xx2 = fminf(ix2, bx2[k]), yy2 = fminf(iy2, by2[k]);
                float inter = fmaxf(xx2 - xx1, 0.f) * fmaxf(yy2 - yy1, 0.f);
                float iou = inter / (ia + bar[k] - inter + 1e-14f);
                sup = iou > 0.5f;
            }
            unsigned long long m = __ballot(sup);
            if (lane == 0) smask[i][k] = m;
        }
    }
    __syncthreads();
    unsigned long long keep[4];
    #pragma unroll
    for (int k = 0; k < 4; k++) {
        int cidx = k * 64 + lane;
        bool valid = (cidx < NCELLS) && (ssort[cidx] > 0.01f);
        keep[k] = __ballot(valid);
    }
    #pragma unroll
    for (int wi = 0; wi < 4; wi++) {
        int base = wi * 64;
        int lim = (NCELLS - base < 64) ? (NCELLS - base) : 64;
        for (int t = 0; t < lim; t++) {
            if ((keep[wi] >> t) & 1ull) {
                int i = base + t;
                keep[0] &= ~smask[i][0];
                keep[1] &= ~smask[i][1];
                keep[2] &= ~smask[i][2];
                keep[3] &= ~smask[i][3];
            }
        }
    }
    if (j < NCELLS) {
        bool kept = (keep[w] >> lane) & 1ull;
        out[(((size_t)b * NCELLS) + ord[j]) * 24 + 4 + c] = kept ? ssort[j] : 0.f;
    }
}

// ---- launch ----
extern "C" void kernel_launch(void* const* d_in, const int* in_sizes, int n_in,
                              void* d_out, int out_size, void* d_ws, size_t ws_size,
                              hipStream_t stream) {
    const float* x  = (const float*)d_in[0];
    const float* w1 = (const float*)d_in[1];
    const float* w2 = (const float*)d_in[2];
    const float* w3 = (const float*)d_in[3];
    const float* w4 = (const float*)d_in[4];
    const float* w5 = (const float*)d_in[5];
    const float* wh = (const float*)d_in[6];
    float* out = (float*)d_out;
    char* base = (char*)d_ws;

    // region A (0 .. 102,760,448)
    unsigned short* a1h = (unsigned short*)(base);
    unsigned short* a1l = a1h + 25690112;
    unsigned short* a3h = (unsigned short*)(base);          // overlays a1 (dead after conv2)
    unsigned short* a3l = a3h + 6422528;
    float* part4 = (float*)(base + 25690112);               // 2 x 3,211,264 fp32
    float* part5 = (float*)(base);                          // 8 x 802,816 fp32 (a3 dead)
    unsigned short* a5h = (unsigned short*)(base + 51380224);
    unsigned short* a5l = a5h + 802816;
    float* clsb = (float*)(base + 54746240);
    // region B (102,760,448 .. 154,140,672)
    unsigned short* a2h = (unsigned short*)(base + 102760448);
    unsigned short* a2l = a2h + 12845056;
    unsigned short* a4h = (unsigned short*)(base + 102760448);  // overlays a2 (dead after conv3)
    unsigned short* a4l = a4h + 3211264;
    // weights
    unsigned short* w2h = (unsigned short*)(base + 154140672);
    unsigned short* w3h = w2h + 73728;
    unsigned short* w4h = w3h + 294912;
    unsigned short* w5h = w4h + 1179648;
    unsigned short* w2l = (unsigned short*)(base + 161955840);
    unsigned short* w3l = w2l + 73728;
    unsigned short* w4l = w3l + 294912;
    unsigned short* w5l = w4l + 1179648;

    prep_all<<<15264, 256, 0, stream>>>(w2, w3, w4, w5,
                                        w2h, w2l, w3h, w3l, w4h, w4l, w5h, w5l);

    conv1_kernel<<<12544, 256, 0, stream>>>(x, w1, a1h, a1l);

    conv_mfma<64, 128, 224, 224, 1, false><<<1568, 256, 0, stream>>>(
        a1h, a1l, w2h, w2l, a2h, a2l, nullptr);
    conv_mfma<128, 256, 112, 112, 1, false><<<784, 256, 0, stream>>>(
        a2h, a2l, w3h, w3l, a3h, a3l, nullptr);
    conv_mfma<256, 512, 56, 56, 2, true><<<1024, 256, 0, stream>>>(
        a3h, a3l, w4h, w4l, nullptr, nullptr, part4);
    reduceN_split<2><<<3136, 256, 0, stream>>>(part4, a4h, a4l, 3211264);
    conv_mfma<512, 512, 28, 28, 8, true><<<1024, 256, 0, stream>>>(
        a4h, a4l, w5h, w5l, nullptr, nullptr, part5);
    reduceN_split<8><<<784, 256, 0, stream>>>(part5, a5h, a5l, 802816);

    head_decode_kernel<<<392, 256, 0, stream>>>(a5h, a5l, wh, out, clsb);
    nms_kernel<<<160, 256, 0, stream>>>(clsb, out, out);
}

// Round 12
// 436.465 us; speedup vs baseline: 1.1176x; 1.0216x over previous
//
#include <hip/hip_runtime.h>
#include <math.h>

#define BATCH 8
#define NCELLS 196
#define NCLS 20
#define HEADC 25

typedef __attribute__((ext_vector_type(8))) short short8;
typedef __attribute__((ext_vector_type(4))) float f32x4;
#define MFMA16(a,b,c) __builtin_amdgcn_mfma_f32_16x16x32_bf16(a,b,c,0,0,0)

// ---- bf16 split helpers (RNE via bit ops; deterministic) ----
__device__ __forceinline__ unsigned short f2bf(float x) {
    union { float f; unsigned u; } a; a.f = x;
    unsigned r = a.u + 0x7FFFu + ((a.u >> 16) & 1u);
    return (unsigned short)(r >> 16);
}
__device__ __forceinline__ float bf2f(unsigned short h) {
    union { unsigned u; float f; } a; a.u = ((unsigned)h) << 16;
    return a.f;
}
__device__ __forceinline__ void split_bf(float x, unsigned short& h, unsigned short& l) {
    h = f2bf(x);
    l = f2bf(x - bf2f(h));
}

// ---- merged weight prep: conv2..conv5 in ONE launch ----
__device__ __forceinline__ void prep_one(const float* __restrict__ w, int CIN, int COUT,
                                         int idx, unsigned short* __restrict__ whi,
                                         unsigned short* __restrict__ wlo) {
    int G = COUT >> 4, CH = CIN >> 5;
    int j    = idx & 7;
    int lane = (idx >> 3) & 63;
    int fg   = idx >> 9;
    int g    = fg % G;
    int fc   = fg / G;
    int chunk = fc % CH;
    int plane = fc / CH;
    int co = g * 16 + (lane & 15);
    int ci = chunk * 32 + (lane >> 4) * 8 + j;
    int ky = plane / 3, kx = plane % 3;
    float v = w[((co * CIN + ci) * 3 + ky) * 3 + kx];
    unsigned short h, l; split_bf(v, h, l);
    whi[idx] = h; wlo[idx] = l;
}
__global__ void prep_all(const float* __restrict__ w2, const float* __restrict__ w3,
                         const float* __restrict__ w4, const float* __restrict__ w5,
                         unsigned short* __restrict__ w2h, unsigned short* __restrict__ w2l,
                         unsigned short* __restrict__ w3h, unsigned short* __restrict__ w3l,
                         unsigned short* __restrict__ w4h, unsigned short* __restrict__ w4l,
                         unsigned short* __restrict__ w5h, unsigned short* __restrict__ w5l) {
    int idx = blockIdx.x * 256 + threadIdx.x;
    const int n2 = 73728, n3 = 294912, n4 = 1179648, n5 = 2359296;
    if (idx < n2) { prep_one(w2, 64, 128, idx, w2h, w2l); return; }
    idx -= n2;
    if (idx < n3) { prep_one(w3, 128, 256, idx, w3h, w3l); return; }
    idx -= n3;
    if (idx < n4) { prep_one(w4, 256, 512, idx, w4h, w4l); return; }
    idx -= n4;
    if (idx < n5) { prep_one(w5, 512, 512, idx, w5h, w5l); }
}

// ---- R12: conv1 FUSED into conv2 ----
// Per block (8x8 conv2-out tile): stage x tile (35x35x3 fp32) + w1 once; per
// 32-co chunk compute the 17x17 a1 tile in fp32 VALU (ReLU+split) straight
// into the swizzled sA layout, then run the R8-exact MFMA plane loop.
// Kills the conv1 dispatch and the 103MB(write)+116MB(read) a1 round-trip.
// LDS = 36,992 + 15,120 + 6,912 = 59,024 B -> 2 blocks/CU.
__launch_bounds__(256, 2)
__global__ void conv2_fused(const float* __restrict__ x, const float* __restrict__ w1,
                            const unsigned short* __restrict__ whi, const unsigned short* __restrict__ wlo,
                            unsigned short* __restrict__ ohi, unsigned short* __restrict__ olo) {
    constexpr int PLANE_E = 17 * 17 * 32;
    __shared__ __align__(16) unsigned short sA[2 * PLANE_E];
    __shared__ float sX[3][35][36];
    __shared__ float sW1[27][64];

    int bid = blockIdx.x;
    int txi = bid % 14;  bid /= 14;
    int tyi = bid % 14;
    int b   = bid / 14;
    int oy0 = tyi * 8, ox0 = txi * 8;       // conv2 out origin
    int ay0 = oy0 * 2, ax0 = ox0 * 2;       // a1 tile origin (17x17)
    int xy0 = ay0 * 2, xx0 = ax0 * 2;       // x tile origin (35x35)

    int tid = threadIdx.x;
    int w   = tid >> 6;
    int lane = tid & 63;
    int n = lane & 15, quad = lane >> 4;

    // stage w1 [27][64]
    for (int e = tid; e < 1728; e += 256)
        sW1[e >> 6][e & 63] = w1[(e & 63) * 27 + (e >> 6)];
    // stage x tile [3][35][35] (+pad col)
    for (int e = tid; e < 3675; e += 256) {
        int ci = e / 1225;
        int r  = (e / 35) % 35;
        int cx = e % 35;
        float v = 0.f;
        if (xy0 + r < 448 && xx0 + cx < 448)
            v = x[(((size_t)b * 3 + ci) * 448 + xy0 + r) * 448 + xx0 + cx];
        sX[ci][r][cx] = v;
    }

    int oyl[4], oxl[4], pbase[4];
    #pragma unroll
    for (int nt = 0; nt < 4; nt++) {
        int oy_off = (nt >> 1) * 4 + (n >> 2);
        int ox_off = (nt & 1) * 4 + (n & 3);
        oyl[nt] = oy0 + oy_off;
        oxl[nt] = ox0 + ox_off;
        pbase[nt] = 2 * oy_off * 17 + 2 * ox_off;
    }
    f32x4 zero = {0.f, 0.f, 0.f, 0.f};
    f32x4 acc[2][4];
    #pragma unroll
    for (int ct = 0; ct < 2; ct++)
        #pragma unroll
        for (int nt = 0; nt < 4; nt++) acc[ct][nt] = zero;
    int g0 = w * 2;                          // COG=1, G=8

    for (int ch = 0; ch < 2; ch++) {         // a1 channel chunks (2 x 32)
        __syncthreads();                     // sA free; (ch=0) sX/sW1 ready
        // ---- compute a1 tile chunk: 289 px x 4 groups of 8 co ----
        for (int e = tid; e < 289 * 4; e += 256) {
            int pxi = e >> 2, g = e & 3;
            int liy = pxi / 17, lix = pxi - liy * 17;
            int co8 = ch * 32 + g * 8;
            union { unsigned short u[8]; uint4 v; } ph, pl;
            if (ay0 + liy < 224 && ax0 + lix < 224) {
                float a0[8] = {0.f,0.f,0.f,0.f,0.f,0.f,0.f,0.f};
                #pragma unroll
                for (int ci = 0; ci < 3; ci++)
                    #pragma unroll
                    for (int ky = 0; ky < 3; ky++) {
                        const float* row = sX[ci][2 * liy + ky];
                        #pragma unroll
                        for (int kx = 0; kx < 3; kx++) {
                            float xv = row[2 * lix + kx];
                            const float* wp = &sW1[ci * 9 + ky * 3 + kx][co8];
                            float4 wa = *(const float4*)wp;
                            float4 wb = *(const float4*)(wp + 4);
                            a0[0] += wa.x * xv; a0[1] += wa.y * xv;
                            a0[2] += wa.z * xv; a0[3] += wa.w * xv;
                            a0[4] += wb.x * xv; a0[5] += wb.y * xv;
                            a0[6] += wb.z * xv; a0[7] += wb.w * xv;
                        }
                    }
                #pragma unroll
                for (int u = 0; u < 8; u++) {
                    float v = fmaxf(a0[u], 0.f);
                    split_bf(v, ph.u[u], pl.u[u]);
                }
            } else {
                ph.v = make_uint4(0u,0u,0u,0u);
                pl.v = make_uint4(0u,0u,0u,0u);
            }
            int u = pxi * 4 + (g ^ ((pxi >> 1) & 3));
            *(uint4*)&sA[u * 8] = ph.v;
            *(uint4*)&sA[PLANE_E + u * 8] = pl.v;
        }
        __syncthreads();
        // ---- MFMA planes (R8-exact) ----
        #pragma unroll
        for (int pl = 0; pl < 9; pl++) {
            size_t fbase = ((size_t)(pl * 2 + ch) * 8 + g0) * 512 + lane * 8;
            short8 Ah0 = *(const short8*)(whi + fbase);
            short8 Ah1 = *(const short8*)(whi + fbase + 512);
            short8 Al0 = *(const short8*)(wlo + fbase);
            short8 Al1 = *(const short8*)(wlo + fbase + 512);
            int dp = (pl / 3) * 17 + (pl % 3);
            #pragma unroll
            for (int nt = 0; nt < 4; nt++) {
                int p = pbase[nt] + dp;
                int u = p * 4 + (quad ^ ((p >> 1) & 3));
                short8 Bh = *(const short8*)&sA[u * 8];
                short8 Bl = *(const short8*)&sA[PLANE_E + u * 8];
                acc[0][nt] = MFMA16(Ah0, Bh, acc[0][nt]);
                acc[0][nt] = MFMA16(Ah0, Bl, acc[0][nt]);
                acc[0][nt] = MFMA16(Al0, Bh, acc[0][nt]);
                acc[1][nt] = MFMA16(Ah1, Bh, acc[1][nt]);
                acc[1][nt] = MFMA16(Ah1, Bl, acc[1][nt]);
                acc[1][nt] = MFMA16(Al1, Bh, acc[1][nt]);
            }
        }
    }
    int cob = w * 32;
    #pragma unroll
    for (int ct = 0; ct < 2; ct++) {
        #pragma unroll
        for (int nt = 0; nt < 4; nt++) {
            size_t base = ((size_t)(b * 112 + oyl[nt]) * 112 + oxl[nt]) * 128
                          + cob + ct * 16 + quad * 4;
            unsigned long long h64 = 0ull, l64 = 0ull;
            #pragma unroll
            for (int r = 0; r < 4; r++) {
                float v = fmaxf(acc[ct][nt][r], 0.f);
                unsigned short hh, ll; split_bf(v, hh, ll);
                h64 |= ((unsigned long long)hh) << (16 * r);
                l64 |= ((unsigned long long)ll) << (16 * r);
            }
            *(unsigned long long*)&ohi[base] = h64;
            *(unsigned long long*)&olo[base] = l64;
        }
    }
}

// ---- MFMA conv (R8-exact structure; ring-3 reverted) ----
template<int CIN, int COUT, int HIN, int WIN, int KSPLIT, bool PARTIAL>
__launch_bounds__(256, 4)
__global__ void conv_mfma(const unsigned short* __restrict__ ahi, const unsigned short* __restrict__ alo,
                          const unsigned short* __restrict__ whi, const unsigned short* __restrict__ wlo,
                          unsigned short* __restrict__ ohi, unsigned short* __restrict__ olo,
                          float* __restrict__ part) {
    constexpr int HOUT = HIN / 2, WOUT = WIN / 2;
    constexpr int TX = (WOUT + 7) / 8, TY = (HOUT + 7) / 8;
    constexpr int COG = COUT / 128;
    constexpr int CH_TOT = CIN / 32;
    constexpr int CH = CH_TOT / KSPLIT;
    constexpr int G = COUT / 16;
    constexpr int PLANE_E = 17 * 17 * 32;
    constexpr size_t PSZ = (size_t)BATCH * HOUT * WOUT * COUT;

    __shared__ __align__(16) unsigned short sA[2 * PLANE_E];

    int bid = blockIdx.x;
    int ks  = bid % KSPLIT; bid /= KSPLIT;
    int txi = bid % TX;     bid /= TX;
    int tyi = bid % TY;     bid /= TY;
    int cg  = bid % COG;
    int b   = bid / COG;
    int oy0 = tyi * 8, ox0 = txi * 8;
    int iy0 = oy0 * 2, ix0 = ox0 * 2;

    int tid = threadIdx.x;
    int w   = tid >> 6;
    int lane = tid & 63;
    int n = lane & 15, quad = lane >> 4;

    int oyl[4], oxl[4], pbase[4];
    #pragma unroll
    for (int nt = 0; nt < 4; nt++) {
        int oyq = nt >> 1, oxq = nt & 1;
        int oy_off = oyq * 4 + (n >> 2);
        int ox_off = oxq * 4 + (n & 3);
        oyl[nt] = oy0 + oy_off;
        oxl[nt] = ox0 + ox_off;
        pbase[nt] = 2 * oy_off * 17 + 2 * ox_off;
    }

    f32x4 zero = {0.f, 0.f, 0.f, 0.f};
    f32x4 acc[2][4];
    #pragma unroll
    for (int ct = 0; ct < 2; ct++)
        #pragma unroll
        for (int nt = 0; nt < 4; nt++) acc[ct][nt] = zero;

    int g0 = cg * 8 + w * 2;

    for (int ch = 0; ch < CH; ch++) {
        int chunk = ks * CH + ch;
        int ci0 = chunk * 32;
        __syncthreads();
        for (int e = tid; e < 17 * 17 * 8; e += 256) {
            int pxi = e >> 3, grp = e & 7;
            int liy = pxi / 17, lix = pxi - liy * 17;
            int iy = iy0 + liy, ix = ix0 + lix;
            uint4 v = make_uint4(0u, 0u, 0u, 0u);
            if (iy < HIN && ix < WIN) {
                const unsigned short* src = ((grp & 4) ? alo : ahi)
                    + ((size_t)(b * HIN + iy) * WIN + ix) * CIN + ci0 + (grp & 3) * 8;
                v = *(const uint4*)src;
            }
            int u = pxi * 4 + ((grp & 3) ^ ((pxi >> 1) & 3));
            *(uint4*)&sA[((grp >> 2) ? PLANE_E : 0) + u * 8] = v;
        }
        __syncthreads();
        #pragma unroll
        for (int pl = 0; pl < 9; pl++) {
            size_t fbase = ((size_t)(pl * CH_TOT + chunk) * G + g0) * 512 + lane * 8;
            short8 Ah0 = *(const short8*)(whi + fbase);
            short8 Ah1 = *(const short8*)(whi + fbase + 512);
            short8 Al0 = *(const short8*)(wlo + fbase);
            short8 Al1 = *(const short8*)(wlo + fbase + 512);
            int dp = (pl / 3) * 17 + (pl % 3);
            #pragma unroll
            for (int nt = 0; nt < 4; nt++) {
                int p = pbase[nt] + dp;
                int u = p * 4 + (quad ^ ((p >> 1) & 3));
                short8 Bh = *(const short8*)&sA[u * 8];
                short8 Bl = *(const short8*)&sA[PLANE_E + u * 8];
                acc[0][nt] = MFMA16(Ah0, Bh, acc[0][nt]);
                acc[0][nt] = MFMA16(Ah0, Bl, acc[0][nt]);
                acc[0][nt] = MFMA16(Al0, Bh, acc[0][nt]);
                acc[1][nt] = MFMA16(Ah1, Bh, acc[1][nt]);
                acc[1][nt] = MFMA16(Ah1, Bl, acc[1][nt]);
                acc[1][nt] = MFMA16(Al1, Bh, acc[1][nt]);
            }
        }
    }
    int cob = cg * 128 + w * 32;
    #pragma unroll
    for (int ct = 0; ct < 2; ct++) {
        #pragma unroll
        for (int nt = 0; nt < 4; nt++) {
            if (oyl[nt] >= HOUT || oxl[nt] >= WOUT) continue;
            size_t base = ((size_t)(b * HOUT + oyl[nt]) * WOUT + oxl[nt]) * COUT
                          + cob + ct * 16 + quad * 4;
            if (PARTIAL) {
                *(f32x4*)&part[(size_t)ks * PSZ + base] = acc[ct][nt];
            } else {
                unsigned long long h64 = 0ull, l64 = 0ull;
                #pragma unroll
                for (int r = 0; r < 4; r++) {
                    float v = fmaxf(acc[ct][nt][r], 0.f);
                    unsigned short hh, ll; split_bf(v, hh, ll);
                    h64 |= ((unsigned long long)hh) << (16 * r);
                    l64 |= ((unsigned long long)ll) << (16 * r);
                }
                *(unsigned long long*)&ohi[base] = h64;
                *(unsigned long long*)&olo[base] = l64;
            }
        }
    }
}

// ---- reduce KS K-split fp32 partials -> ReLU -> hi/lo bf16 ----
template<int KS>
__global__ void reduceN_split(const float* __restrict__ p, unsigned short* __restrict__ oh,
                              unsigned short* __restrict__ ol, int n) {
    int n4 = n >> 2;
    int i = blockIdx.x * 256 + threadIdx.x;
    if (i >= n4) return;
    const float4* p4 = (const float4*)p;
    float4 s = p4[i];
    #pragma unroll
    for (int k = 1; k < KS; k++) {
        float4 t = p4[i + (size_t)k * n4];
        s.x += t.x; s.y += t.y; s.z += t.z; s.w += t.w;
    }
    float v[4] = { fmaxf(s.x,0.f), fmaxf(s.y,0.f), fmaxf(s.z,0.f), fmaxf(s.w,0.f) };
    unsigned long long h64 = 0ull, l64 = 0ull;
    #pragma unroll
    for (int r = 0; r < 4; r++) {
        unsigned short hh, ll; split_bf(v[r], hh, ll);
        h64 |= ((unsigned long long)hh) << (16 * r);
        l64 |= ((unsigned long long)ll) << (16 * r);
    }
    *(unsigned long long*)&oh[i * 4] = h64;
    *(unsigned long long*)&ol[i * 4] = l64;
}

// ---- fused 1x1 head + decode ----
__global__ void head_decode_kernel(const unsigned short* __restrict__ ah,
                                   const unsigned short* __restrict__ al,
                                   const float* __restrict__ wh,
                                   float* __restrict__ out, float* __restrict__ cls) {
    int wave = threadIdx.x >> 6;
    int lane = threadIdx.x & 63;
    int cellid = blockIdx.x * 4 + wave;
    float acc[HEADC];
    #pragma unroll
    for (int c = 0; c < HEADC; c++) acc[c] = 0.f;
    for (int it = 0; it < 8; it++) {
        int ci = it * 64 + lane;
        size_t idx = (size_t)cellid * 512 + ci;
        float a = bf2f(ah[idx]) + bf2f(al[idx]);
        #pragma unroll
        for (int c = 0; c < HEADC; c++) acc[c] += a * wh[c * 512 + ci];
    }
    #pragma unroll
    for (int c = 0; c < HEADC; c++) {
        float v = acc[c];
        v += __shfl_down(v, 32); v += __shfl_down(v, 16); v += __shfl_down(v, 8);
        v += __shfl_down(v, 4);  v += __shfl_down(v, 2);  v += __shfl_down(v, 1);
        acc[c] = v;
    }
    if (lane == 0) {
        int cell = cellid % NCELLS;
        int gx = cell % 14, gy = cell / 14;
        float conf = 1.f / (1.f + expf(-acc[0]));
        float m = acc[1];
        #pragma unroll
        for (int c = 1; c < NCLS; c++) m = fmaxf(m, acc[1 + c]);
        float e[NCLS], s = 0.f;
        #pragma unroll
        for (int c = 0; c < NCLS; c++) { e[c] = expf(acc[1 + c] - m); s += e[c]; }
        float inv = conf / s;
        #pragma unroll
        for (int c = 0; c < NCLS; c++) cls[(size_t)cellid * NCLS + c] = e[c] * inv;
        float cx = (1.f / (1.f + expf(-acc[21])) + gx) * 32.f;
        float cy = (1.f / (1.f + expf(-acc[22])) + gy) * 32.f;
        float bw = expf(acc[23]) * 32.f;
        float bh = expf(acc[24]) * 32.f;
        float x1 = (cx - 0.5f * bw) / 448.f, y1 = (cy - 0.5f * bh) / 448.f;
        float x2 = (cx + 0.5f * bw) / 448.f, y2 = (cy + 0.5f * bh) / 448.f;
        x1 = fminf(fmaxf(x1, 0.f), 1.f); y1 = fminf(fmaxf(y1, 0.f), 1.f);
        x2 = fminf(fmaxf(x2, 0.f), 1.f); y2 = fminf(fmaxf(y2, 0.f), 1.f);
        float* o = out + (size_t)cellid * 24;
        o[0] = x1; o[1] = y1; o[2] = x2; o[3] = y2;
    }
}

// ---- NMS with inline IoU (boxes staged in LDS) ----
__global__ void nms_kernel(const float* __restrict__ cls, const float* __restrict__ boxes,
                           float* __restrict__ out) {
    int b = blockIdx.x / NCLS;
    int c = blockIdx.x % NCLS;
    __shared__ float sc[NCELLS];
    __shared__ float ssort[NCELLS];
    __shared__ int   ord[NCELLS];
    __shared__ __align__(16) float sbox[NCELLS][4];
    __shared__ float sarea[NCELLS];
    __shared__ __align__(16) unsigned long long smask[NCELLS][4];
    int j = threadIdx.x;
    int lane = j & 63;
    int w = j >> 6;
    float sj = 0.f;
    if (j < NCELLS) {
        sj = cls[(((size_t)b * NCELLS) + j) * NCLS + c];
        sc[j] = sj;
        float4 bx = *(const float4*)&boxes[(((size_t)b * NCELLS) + j) * 24];
        *(float4*)sbox[j] = bx;
        sarea[j] = fmaxf(bx.z - bx.x, 0.f) * fmaxf(bx.w - bx.y, 0.f);
    }
    __syncthreads();
    if (j < NCELLS) {
        int r = 0;
        for (int k = 0; k < NCELLS; k++) {
            float sk = sc[k];
            r += (sk > sj) || (sk == sj && k < j);
        }
        ord[r] = j; ssort[r] = sj;
    }
    __syncthreads();
    int oc[4]; float bx1[4], by1[4], bx2[4], by2[4], bar[4];
    #pragma unroll
    for (int k = 0; k < 4; k++) {
        int cidx = k * 64 + lane;
        oc[k] = (cidx < NCELLS) ? ord[cidx] : 0;
        bx1[k] = sbox[oc[k]][0]; by1[k] = sbox[oc[k]][1];
        bx2[k] = sbox[oc[k]][2]; by2[k] = sbox[oc[k]][3];
        bar[k] = sarea[oc[k]];
    }
    for (int i = w; i < NCELLS; i += 4) {
        int oi = ord[i];
        float ix1 = sbox[oi][0], iy1 = sbox[oi][1];
        float ix2 = sbox[oi][2], iy2 = sbox[oi][3];
        float ia  = sarea[oi];
        #pragma unroll
        for (int k = 0; k < 4; k++) {
            int cidx = k * 64 + lane;
            bool sup = false;
            if (cidx < NCELLS && cidx > i) {
                float xx1 = fmaxf(ix1, bx1[k]), yy1 = fmaxf(iy1, by1[k]);
                float xx2 = fminf(ix2, bx2[k]), yy2 = fminf(iy2, by2[k]);
                float inter = fmaxf(xx2 - xx1, 0.f) * fmaxf(yy2 - yy1, 0.f);
                float iou = inter / (ia + bar[k] - inter + 1e-14f);
                sup = iou > 0.5f;
            }
            unsigned long long m = __ballot(sup);
            if (lane == 0) smask[i][k] = m;
        }
    }
    __syncthreads();
    unsigned long long keep[4];
    #pragma unroll
    for (int k = 0; k < 4; k++) {
        int cidx = k * 64 + lane;
        bool valid = (cidx < NCELLS) && (ssort[cidx] > 0.01f);
        keep[k] = __ballot(valid);
    }
    #pragma unroll
    for (int wi = 0; wi < 4; wi++) {
        int base = wi * 64;
        int lim = (NCELLS - base < 64) ? (NCELLS - base) : 64;
        for (int t = 0; t < lim; t++) {
            if ((keep[wi] >> t) & 1ull) {
                int i = base + t;
                keep[0] &= ~smask[i][0];
                keep[1] &= ~smask[i][1];
                keep[2] &= ~smask[i][2];
                keep[3] &= ~smask[i][3];
            }
        }
    }
    if (j < NCELLS) {
        bool kept = (keep[w] >> lane) & 1ull;
        out[(((size_t)b * NCELLS) + ord[j]) * 24 + 4 + c] = kept ? ssort[j] : 0.f;
    }
}

// ---- launch ----
extern "C" void kernel_launch(void* const* d_in, const int* in_sizes, int n_in,
                              void* d_out, int out_size, void* d_ws, size_t ws_size,
                              hipStream_t stream) {
    const float* x  = (const float*)d_in[0];
    const float* w1 = (const float*)d_in[1];
    const float* w2 = (const float*)d_in[2];
    const float* w3 = (const float*)d_in[3];
    const float* w4 = (const float*)d_in[4];
    const float* w5 = (const float*)d_in[5];
    const float* wh = (const float*)d_in[6];
    float* out = (float*)d_out;
    char* base = (char*)d_ws;

    // region A
    unsigned short* a3h = (unsigned short*)(base);
    unsigned short* a3l = a3h + 6422528;
    float* part4 = (float*)(base + 25690112);               // 2 x 3,211,264 fp32
    float* part5 = (float*)(base);                          // 8 x 802,816 fp32 (a3 dead)
    unsigned short* a5h = (unsigned short*)(base + 51380224);
    unsigned short* a5l = a5h + 802816;
    float* clsb = (float*)(base + 54746240);
    // region B
    unsigned short* a2h = (unsigned short*)(base + 102760448);
    unsigned short* a2l = a2h + 12845056;
    unsigned short* a4h = (unsigned short*)(base + 102760448);  // overlays a2 (dead after conv3)
    unsigned short* a4l = a4h + 3211264;
    // weights
    unsigned short* w2h = (unsigned short*)(base + 154140672);
    unsigned short* w3h = w2h + 73728;
    unsigned short* w4h = w3h + 294912;
    unsigned short* w5h = w4h + 1179648;
    unsigned short* w2l = (unsigned short*)(base + 161955840);
    unsigned short* w3l = w2l + 73728;
    unsigned short* w4l = w3l + 294912;
    unsigned short* w5l = w4l + 1179648;

    prep_all<<<15264, 256, 0, stream>>>(w2, w3, w4, w5,
                                        w2h, w2l, w3h, w3l, w4h, w4l, w5h, w5l);

    // conv1+conv2 fused: 8b * 14*14 tiles = 1568 blocks
    conv2_fused<<<1568, 256, 0, stream>>>(x, w1, w2h, w2l, a2h, a2l);

    conv_mfma<128, 256, 112, 112, 1, false><<<784, 256, 0, stream>>>(
        a2h, a2l, w3h, w3l, a3h, a3l, nullptr);
    conv_mfma<256, 512, 56, 56, 2, true><<<1024, 256, 0, stream>>>(
        a3h, a3l, w4h, w4l, nullptr, nullptr, part4);
    reduceN_split<2><<<3136, 256, 0, stream>>>(part4, a4h, a4l, 3211264);
    conv_mfma<512, 512, 28, 28, 8, true><<<1024, 256, 0, stream>>>(
        a4h, a4l, w5h, w5l, nullptr, nullptr, part5);
    reduceN_split<8><<<784, 256, 0, stream>>>(part5, a5h, a5l, 802816);

    head_decode_kernel<<<392, 256, 0, stream>>>(a5h, a5l, wh, out, clsb);
    nms_kernel<<<160, 256, 0, stream>>>(clsb, out, out);
}